// Round 10
// baseline (345.244 us; speedup 1.0000x reference)
//
#include <hip/hip_runtime.h>
#include <hip/hip_bf16.h>

typedef __attribute__((ext_vector_type(8))) short s8v;   // 8 x bf16 MFMA operand
typedef __attribute__((ext_vector_type(4))) float f4v;   // MFMA accumulator
typedef __attribute__((ext_vector_type(4))) unsigned short us4;
typedef unsigned short u16;

__device__ __forceinline__ u16 f2bf(float f) {
  union { float f; unsigned int u; } x;
  x.f = f;
  unsigned int lsb = (x.u >> 16) & 1u;
  return (u16)((x.u + 0x7fffu + lsb) >> 16);
}

__device__ __forceinline__ float bf2f(u16 u) {
  union { unsigned int i; float f; } x;
  x.i = ((unsigned int)u) << 16;
  return x.f;
}

__device__ __forceinline__ uint4 pack8(float4 a, float4 b) {
  union { u16 u[8]; uint4 v; } t;
  t.u[0] = f2bf(a.x); t.u[1] = f2bf(a.y); t.u[2] = f2bf(a.z); t.u[3] = f2bf(a.w);
  t.u[4] = f2bf(b.x); t.u[5] = f2bf(b.y); t.u[6] = f2bf(b.z); t.u[7] = f2bf(b.w);
  return t.v;
}

// ---------------------------------------------------------------------------
// Kernel 1: projections (unchanged). C[16384x256] = A[16384x512] @ W[512x256].
// ---------------------------------------------------------------------------
__global__ __launch_bounds__(256) void proj_kernel(
    const float* __restrict__ inputs, const float* __restrict__ memory,
    const float* __restrict__ Wq, const float* __restrict__ Wk,
    u16* __restrict__ qb, u16* __restrict__ krow, u16* __restrict__ kcol)
{
  __shared__ u16 Wt[64 * 264];
  __shared__ u16 At[64 * 40];

  const int tid = threadIdx.x;
  const int w = tid >> 6;
  const int l = tid & 63;
  const int lr = l & 15;
  const int lh = l >> 4;
  const int rbase = blockIdx.x * 64;
  const int n0 = blockIdx.y * 64;
  const int src = blockIdx.z;
  const float* __restrict__ A  = src ? memory : inputs;
  const float* __restrict__ Wg = src ? Wk : Wq;

  f4v acc[4];
#pragma unroll
  for (int i = 0; i < 4; ++i) acc[i] = f4v{0.f, 0.f, 0.f, 0.f};

  for (int kh = 0; kh < 2; ++kh) {
    {
      const int kl = tid >> 3;
      const int nl = (tid & 7) * 8;
#pragma unroll
      for (int i = 0; i < 8; ++i) {
        const int k = kl + i * 32;
        const float* s = Wg + (size_t)(kh * 256 + k) * 256 + n0 + nl;
        float4 x0 = *(const float4*)s;
        float4 x1 = *(const float4*)(s + 4);
        Wt[(nl + 0) * 264 + k] = f2bf(x0.x);
        Wt[(nl + 1) * 264 + k] = f2bf(x0.y);
        Wt[(nl + 2) * 264 + k] = f2bf(x0.z);
        Wt[(nl + 3) * 264 + k] = f2bf(x0.w);
        Wt[(nl + 4) * 264 + k] = f2bf(x1.x);
        Wt[(nl + 5) * 264 + k] = f2bf(x1.y);
        Wt[(nl + 6) * 264 + k] = f2bf(x1.z);
        Wt[(nl + 7) * 264 + k] = f2bf(x1.w);
      }
    }
    __syncthreads();
    for (int ks = 0; ks < 8; ++ks) {
      {
        const int row = tid >> 2;
        const int kk = (tid & 3) * 8;
        const float* s = A + (size_t)(rbase + row) * 512 + kh * 256 + ks * 32 + kk;
        float4 x0 = *(const float4*)s;
        float4 x1 = *(const float4*)(s + 4);
        *(uint4*)&At[row * 40 + kk] = pack8(x0, x1);
      }
      __syncthreads();
      const s8v af = *(const s8v*)&At[(w * 16 + lr) * 40 + lh * 8];
#pragma unroll
      for (int nt = 0; nt < 4; ++nt) {
        const s8v bf = *(const s8v*)&Wt[(nt * 16 + lr) * 264 + ks * 32 + lh * 8];
        acc[nt] = __builtin_amdgcn_mfma_f32_16x16x32_bf16(af, bf, acc[nt], 0, 0, 0);
      }
      __syncthreads();
    }
  }

  u16* __restrict__ dst = src ? krow : qb;
#pragma unroll
  for (int nt = 0; nt < 4; ++nt) {
    const int col = n0 + nt * 16 + lr;
    const int R0 = rbase + w * 16 + lh * 4;
    u16 u0 = f2bf(acc[nt][0]);
    u16 u1 = f2bf(acc[nt][1]);
    u16 u2 = f2bf(acc[nt][2]);
    u16 u3 = f2bf(acc[nt][3]);
    dst[(size_t)(R0 + 0) * 256 + col] = u0;
    dst[(size_t)(R0 + 1) * 256 + col] = u1;
    dst[(size_t)(R0 + 2) * 256 + col] = u2;
    dst[(size_t)(R0 + 3) * 256 + col] = u3;
    if (src) {
      const int bb = R0 >> 11;
      const int mm = R0 & 2047;
      us4 pk;
      pk[0] = u0; pk[1] = u1; pk[2] = u2; pk[3] = u3;
      *(us4*)&kcol[((size_t)bb * 256 + col) * 2048 + mm] = pk;
    }
  }
}

// ---------------------------------------------------------------------------
// Kernel 2: QK^T + exp once. 2-phase double-buffered K staging, one barrier
// per iter. pb stores are PLAIN (allocating) so partial-line writes merge in
// L2 — NT was the write-amplification suspect. 4-way M split.
// ---------------------------------------------------------------------------
__global__ __launch_bounds__(256) void attn_sum_kernel(
    const u16* __restrict__ qb, const u16* __restrict__ krow,
    const int* __restrict__ mlens, const int* __restrict__ qlens,
    float* __restrict__ psum_p, u16* __restrict__ pb)
{
  __shared__ u16 kr[2][32 * 264];
  __shared__ u16 pl[4 * 16 * 40];

  const int tid = threadIdx.x;
  const int w = tid >> 6;
  const int l = tid & 63;
  const int lr = l & 15;
  const int lh = l >> 4;
  const int b = blockIdx.y;
  const int q0 = blockIdx.x * 64;
  const int ms = blockIdx.z;
  const int m_base = ms * 512;
  const int mlen = mlens[b];
  const int qlen = qlens[b];
  const int qrow0 = q0 + w * 16 + lh * 4;

  const int sm = tid >> 5;          // base m row (0..7), +8 per chunk
  const int sG = tid & 31;          // 16B granule within row

  s8v qf[8];
  {
    const u16* qp = qb + ((size_t)b * 2048 + q0 + w * 16 + lr) * 256 + lh * 8;
#pragma unroll
    for (int s = 0; s < 8; ++s) qf[s] = *(const s8v*)(qp + s * 32);
  }

  float psum[4] = {0.f, 0.f, 0.f, 0.f};
  const float C2 = 0.09016844005556021f;  // log2(e)/16

  uint4 st[4];
#pragma unroll
  for (int i = 0; i < 4; ++i)
    st[i] = *(const uint4*)(krow + (((size_t)b * 2048 + m_base + sm + i * 8) << 8) + sG * 8);
#pragma unroll
  for (int i = 0; i < 4; ++i)
    *(uint4*)&kr[0][(sm + i * 8) * 264 + sG * 8] = st[i];
  __syncthreads();

  for (int t = 0; t < 16; ++t) {
    const int m0 = m_base + t * 32;
    const int cur = t & 1;

    if (t < 15) {
#pragma unroll
      for (int i = 0; i < 4; ++i)
        st[i] = *(const uint4*)(krow + (((size_t)b * 2048 + m0 + 32 + sm + i * 8) << 8) + sG * 8);
    }

    f4v sacc[2];
    sacc[0] = f4v{0.f, 0.f, 0.f, 0.f};
    sacc[1] = f4v{0.f, 0.f, 0.f, 0.f};
#pragma unroll
    for (int s = 0; s < 8; ++s) {
#pragma unroll
      for (int f = 0; f < 2; ++f) {
        const s8v bf = *(const s8v*)&kr[cur][(f * 16 + lr) * 264 + s * 32 + lh * 8];
        sacc[f] = __builtin_amdgcn_mfma_f32_16x16x32_bf16(qf[s], bf, sacc[f], 0, 0, 0);
      }
    }

#pragma unroll
    for (int f = 0; f < 2; ++f) {
      const int m = m0 + f * 16 + lr;
      const bool vm = m < mlen;
#pragma unroll
      for (int r = 0; r < 4; ++r) {
        float p = exp2f(sacc[f][r] * C2);
        if (!vm) p = 0.f;
        if (qrow0 + r >= qlen) p = 1.f;
        psum[r] += p;
        pl[w * 640 + (lh * 4 + r) * 40 + f * 16 + lr] = f2bf(p);
      }
    }

    // per-wave transpose re-read -> pb (PV A-frag layout), PLAIN store
    const s8v pav = *(const s8v*)&pl[w * 640 + lr * 40 + lh * 8];
    *(s8v*)(pb + ((size_t)b * 2048 + q0 + w * 16 + lr) * 2048 + m0 + lh * 8) = pav;

    if (t < 15) {
#pragma unroll
      for (int i = 0; i < 4; ++i)
        *(uint4*)&kr[cur ^ 1][(sm + i * 8) * 264 + sG * 8] = st[i];
    }
    __syncthreads();
  }

#pragma unroll
  for (int r = 0; r < 4; ++r) {
    float v = psum[r];
    v += __shfl_xor(v, 1);
    v += __shfl_xor(v, 2);
    v += __shfl_xor(v, 4);
    v += __shfl_xor(v, 8);
    psum[r] = v;
  }
  if (lr == 0) {
#pragma unroll
    for (int r = 0; r < 4; ++r)
      psum_p[ms * 16384 + b * 2048 + qrow0 + r] = psum[r];
  }
}

// ---------------------------------------------------------------------------
// Kernel 3: PV + normalized writes. 2-phase double-buffered V staging +
// P prefetch. ONE barrier per iter. ALL output stores PLAIN (allocating) —
// the NT streaming stores were the write-amplification suspect. NT kept only
// on the pb streaming LOAD. 3-way M split.
// ---------------------------------------------------------------------------
__global__ __launch_bounds__(256) void pv_kernel(
    const u16* __restrict__ pb, const u16* __restrict__ kcol,
    const float* __restrict__ psum_p, float* __restrict__ out_align,
    float* __restrict__ out_ctx, float* __restrict__ octx_ws)
{
  __shared__ u16 kc[2][256 * 40];

  const int tid = threadIdx.x;
  const int w = tid >> 6;
  const int wq = w >> 1;
  const int wa = w & 1;
  const int l = tid & 63;
  const int lr = l & 15;
  const int lh = l >> 4;
  const int b = blockIdx.y;
  const int qb32 = blockIdx.x * 32;
  const int mh = blockIdx.z;
  const int mstart = (mh == 0) ? 0 : (mh == 1 ? 704 : 1376);
  const int nt = (mh == 0) ? 22 : 21;   // tiles of 32 m

  const int sa = tid >> 2;          // a row (0..63), +64 per chunk
  const int sg = tid & 3;           // 8-m granule

  const int qa = qb32 + wq * 16 + lr;
  float inv_a;
  {
    const int q = b * 2048 + qa;
    inv_a = 1.0f / (psum_p[q] + psum_p[16384 + q] + psum_p[32768 + q] + psum_p[49152 + q]);
  }
  float inv_c[4];
#pragma unroll
  for (int r = 0; r < 4; ++r) {
    const int q = b * 2048 + qb32 + wq * 16 + lh * 4 + r;
    inv_c[r] = 1.0f / (psum_p[q] + psum_p[16384 + q] + psum_p[32768 + q] + psum_p[49152 + q]);
  }

  f4v oacc[8];
#pragma unroll
  for (int i = 0; i < 8; ++i) oacc[i] = f4v{0.f, 0.f, 0.f, 0.f};

  const u16* __restrict__ prow = pb + ((size_t)b * 2048 + qa) * 2048;

  uint4 st[4];
#pragma unroll
  for (int i = 0; i < 4; ++i)
    st[i] = *(const uint4*)(kcol + (((size_t)b * 256 + sa + i * 64) << 11) + mstart + sg * 8);
#pragma unroll
  for (int i = 0; i < 4; ++i)
    *(uint4*)&kc[0][(sa + i * 64) * 40 + sg * 8] = st[i];
  s8v pa = __builtin_nontemporal_load((const s8v*)(prow + mstart + lh * 8));
  __syncthreads();

  for (int t = 0; t < nt; ++t) {
    const int m0 = mstart + t * 32;
    const int cur = t & 1;

    s8v pa_n;
    if (t < nt - 1) {
#pragma unroll
      for (int i = 0; i < 4; ++i)
        st[i] = *(const uint4*)(kcol + (((size_t)b * 256 + sa + i * 64) << 11) + m0 + 32 + sg * 8);
      pa_n = __builtin_nontemporal_load((const s8v*)(prow + m0 + 32 + lh * 8));
    }

    if (wa == 0) {
      f4v f0, f1;
      f0[0] = bf2f((u16)pa[0]) * inv_a; f0[1] = bf2f((u16)pa[1]) * inv_a;
      f0[2] = bf2f((u16)pa[2]) * inv_a; f0[3] = bf2f((u16)pa[3]) * inv_a;
      f1[0] = bf2f((u16)pa[4]) * inv_a; f1[1] = bf2f((u16)pa[5]) * inv_a;
      f1[2] = bf2f((u16)pa[6]) * inv_a; f1[3] = bf2f((u16)pa[7]) * inv_a;
      float* ap = out_align + ((size_t)b * 2048 + qa) * 2048 + m0 + lh * 8;
      *(f4v*)ap = f0;                 // PLAIN stores: merge in L2
      *(f4v*)(ap + 4) = f1;
    }

#pragma unroll
    for (int at = 0; at < 8; ++at) {
      const s8v vf = *(const s8v*)&kc[cur][(wa * 128 + at * 16 + lr) * 40 + lh * 8];
      oacc[at] = __builtin_amdgcn_mfma_f32_16x16x32_bf16(pa, vf, oacc[at], 0, 0, 0);
    }

    if (t < nt - 1) {
#pragma unroll
      for (int i = 0; i < 4; ++i)
        *(uint4*)&kc[cur ^ 1][(sa + i * 64) * 40 + sg * 8] = st[i];
      pa = pa_n;
    }
    __syncthreads();
  }

  float* __restrict__ dst = (mh == 0) ? out_ctx : (octx_ws + (size_t)(mh - 1) * 4194304);
#pragma unroll
  for (int at = 0; at < 8; ++at) {
    const int a = wa * 128 + at * 16 + lr;
#pragma unroll
    for (int r = 0; r < 4; ++r) {
      dst[((size_t)b * 2048 + qb32 + wq * 16 + lh * 4 + r) * 256 + a] =
          oacc[at][r] * inv_c[r];
    }
  }
}

// ---------------------------------------------------------------------------
// Kernel 4: out_ctx += octx_ws[0] + octx_ws[1]
// ---------------------------------------------------------------------------
__global__ __launch_bounds__(256) void combine_kernel(
    float* __restrict__ out_ctx, const float* __restrict__ octx_ws)
{
  const size_t i = (size_t)blockIdx.x * 256 + threadIdx.x;
  float4 a = ((const float4*)out_ctx)[i];
  float4 c0 = ((const float4*)octx_ws)[i];
  float4 c1 = ((const float4*)(octx_ws + 4194304))[i];
  a.x += c0.x + c1.x; a.y += c0.y + c1.y;
  a.z += c0.z + c1.z; a.w += c0.w + c1.w;
  ((float4*)out_ctx)[i] = a;
}

extern "C" void kernel_launch(void* const* d_in, const int* in_sizes, int n_in,
                              void* d_out, int out_size, void* d_ws, size_t ws_size,
                              hipStream_t stream) {
  const float* inputs = (const float*)d_in[0];   // [8,2048,512]
  const float* memory = (const float*)d_in[1];   // [8,2048,512]
  const int* mlens    = (const int*)d_in[2];     // [8]
  const int* qlens    = (const int*)d_in[3];     // [8]
  const float* Wq     = (const float*)d_in[4];   // [512,256]
  const float* Wk     = (const float*)d_in[5];   // [512,256]
  (void)in_sizes; (void)n_in; (void)out_size; (void)ws_size;

  u16* wsu = (u16*)d_ws;
  u16* qb   = wsu;                        // 4194304 u16 (8 MB)
  u16* krow = wsu + 4194304;              // 4194304 u16 (8 MB)
  u16* kcol = wsu + 8388608;              // 4194304 u16 (8 MB)
  float* psum_p = (float*)(wsu + 12582912);   // 4*16384 f32 (256 KB)
  u16* pbuf = wsu + 12713984;             // 33554432 u16 (67 MB)
  float* octx_ws = (float*)(wsu + 46268416);  // 2*4194304 f32 (33.6 MB)

  float* out_ctx = (float*)d_out;             // [8,2048,256]
  float* out_align = out_ctx + 4194304;       // [8,2048,2048]

  proj_kernel<<<dim3(256, 4, 2), dim3(256), 0, stream>>>(
      inputs, memory, Wq, Wk, qb, krow, kcol);
  attn_sum_kernel<<<dim3(32, 8, 4), dim3(256), 0, stream>>>(
      qb, krow, mlens, qlens, psum_p, pbuf);
  pv_kernel<<<dim3(64, 8, 3), dim3(256), 0, stream>>>(
      pbuf, kcol, psum_p, out_align, out_ctx, octx_ws);
  combine_kernel<<<dim3(4096), dim3(256), 0, stream>>>(out_ctx, octx_ws);
}

// Round 11
// 244.043 us; speedup vs baseline: 1.4147x; 1.4147x over previous
//
#include <hip/hip_runtime.h>
#include <hip/hip_bf16.h>

typedef __attribute__((ext_vector_type(8))) short s8v;   // 8 x bf16 MFMA operand
typedef __attribute__((ext_vector_type(4))) float f4v;   // MFMA accumulator
typedef __attribute__((ext_vector_type(4))) unsigned short us4;
typedef unsigned short u16;

__device__ __forceinline__ u16 f2bf(float f) {
  union { float f; unsigned int u; } x;
  x.f = f;
  unsigned int lsb = (x.u >> 16) & 1u;
  return (u16)((x.u + 0x7fffu + lsb) >> 16);
}

__device__ __forceinline__ uint4 pack8(float4 a, float4 b) {
  union { u16 u[8]; uint4 v; } t;
  t.u[0] = f2bf(a.x); t.u[1] = f2bf(a.y); t.u[2] = f2bf(a.z); t.u[3] = f2bf(a.w);
  t.u[4] = f2bf(b.x); t.u[5] = f2bf(b.y); t.u[6] = f2bf(b.z); t.u[7] = f2bf(b.w);
  return t.v;
}

// ---------------------------------------------------------------------------
// Kernel 1: projections. C[16384x256] = A[16384x512] @ W[512x256], bf16 out.
// src=0: queries -> qb row-major; src=1: keys -> krow row-major + kcol [b][a][m]
// ---------------------------------------------------------------------------
__global__ __launch_bounds__(256) void proj_kernel(
    const float* __restrict__ inputs, const float* __restrict__ memory,
    const float* __restrict__ Wq, const float* __restrict__ Wk,
    u16* __restrict__ qb, u16* __restrict__ krow, u16* __restrict__ kcol)
{
  __shared__ u16 Wt[64 * 264];
  __shared__ u16 At[64 * 40];

  const int tid = threadIdx.x;
  const int w = tid >> 6;
  const int l = tid & 63;
  const int lr = l & 15;
  const int lh = l >> 4;
  const int rbase = blockIdx.x * 64;
  const int n0 = blockIdx.y * 64;
  const int src = blockIdx.z;
  const float* __restrict__ A  = src ? memory : inputs;
  const float* __restrict__ Wg = src ? Wk : Wq;

  f4v acc[4];
#pragma unroll
  for (int i = 0; i < 4; ++i) acc[i] = f4v{0.f, 0.f, 0.f, 0.f};

  for (int kh = 0; kh < 2; ++kh) {
    {
      const int kl = tid >> 3;
      const int nl = (tid & 7) * 8;
#pragma unroll
      for (int i = 0; i < 8; ++i) {
        const int k = kl + i * 32;
        const float* s = Wg + (size_t)(kh * 256 + k) * 256 + n0 + nl;
        float4 x0 = *(const float4*)s;
        float4 x1 = *(const float4*)(s + 4);
        Wt[(nl + 0) * 264 + k] = f2bf(x0.x);
        Wt[(nl + 1) * 264 + k] = f2bf(x0.y);
        Wt[(nl + 2) * 264 + k] = f2bf(x0.z);
        Wt[(nl + 3) * 264 + k] = f2bf(x0.w);
        Wt[(nl + 4) * 264 + k] = f2bf(x1.x);
        Wt[(nl + 5) * 264 + k] = f2bf(x1.y);
        Wt[(nl + 6) * 264 + k] = f2bf(x1.z);
        Wt[(nl + 7) * 264 + k] = f2bf(x1.w);
      }
    }
    __syncthreads();
    for (int ks = 0; ks < 8; ++ks) {
      {
        const int row = tid >> 2;
        const int kk = (tid & 3) * 8;
        const float* s = A + (size_t)(rbase + row) * 512 + kh * 256 + ks * 32 + kk;
        float4 x0 = *(const float4*)s;
        float4 x1 = *(const float4*)(s + 4);
        *(uint4*)&At[row * 40 + kk] = pack8(x0, x1);
      }
      __syncthreads();
      const s8v af = *(const s8v*)&At[(w * 16 + lr) * 40 + lh * 8];
#pragma unroll
      for (int nt = 0; nt < 4; ++nt) {
        const s8v bf = *(const s8v*)&Wt[(nt * 16 + lr) * 264 + ks * 32 + lh * 8];
        acc[nt] = __builtin_amdgcn_mfma_f32_16x16x32_bf16(af, bf, acc[nt], 0, 0, 0);
      }
      __syncthreads();
    }
  }

  u16* __restrict__ dst = src ? krow : qb;
#pragma unroll
  for (int nt = 0; nt < 4; ++nt) {
    const int col = n0 + nt * 16 + lr;
    const int R0 = rbase + w * 16 + lh * 4;
    u16 u0 = f2bf(acc[nt][0]);
    u16 u1 = f2bf(acc[nt][1]);
    u16 u2 = f2bf(acc[nt][2]);
    u16 u3 = f2bf(acc[nt][3]);
    dst[(size_t)(R0 + 0) * 256 + col] = u0;
    dst[(size_t)(R0 + 1) * 256 + col] = u1;
    dst[(size_t)(R0 + 2) * 256 + col] = u2;
    dst[(size_t)(R0 + 3) * 256 + col] = u3;
    if (src) {
      const int bb = R0 >> 11;
      const int mm = R0 & 2047;
      us4 pk;
      pk[0] = u0; pk[1] = u1; pk[2] = u2; pk[3] = u3;
      *(us4*)&kcol[((size_t)bb * 256 + col) * 2048 + mm] = pk;
    }
  }
}

// ---------------------------------------------------------------------------
// Kernel 2: row-sum pass (round-5 form, measured ~55 us). 64 q x 512 m per
// block, 4-way M split. psum_p[ms][b][q] = partial sum of p~.
// ---------------------------------------------------------------------------
__global__ __launch_bounds__(256) void attn_sum_kernel(
    const u16* __restrict__ qb, const u16* __restrict__ krow,
    const int* __restrict__ mlens, const int* __restrict__ qlens,
    float* __restrict__ psum_p)
{
  __shared__ u16 kr[32 * 264];

  const int tid = threadIdx.x;
  const int w = tid >> 6;
  const int l = tid & 63;
  const int lr = l & 15;
  const int lh = l >> 4;
  const int b = blockIdx.y;
  const int q0 = blockIdx.x * 64;
  const int ms = blockIdx.z;
  const int m_base = ms * 512;
  const int mlen = mlens[b];
  const int qlen = qlens[b];
  const int qrow0 = q0 + w * 16 + lh * 4;

  s8v qf[8];
  {
    const u16* qp = qb + ((size_t)b * 2048 + q0 + w * 16 + lr) * 256 + lh * 8;
#pragma unroll
    for (int s = 0; s < 8; ++s) qf[s] = *(const s8v*)(qp + s * 32);
  }

  float psum[4] = {0.f, 0.f, 0.f, 0.f};
  const float C2 = 0.09016844005556021f;  // log2(e)/16

  for (int mo = 0; mo < 512; mo += 32) {
    const int m0 = m_base + mo;
#pragma unroll
    for (int i = 0; i < 4; ++i) {
      const int idx = i * 256 + tid;
      const int m = idx >> 5, G = idx & 31;
      uint4 v = *(const uint4*)(krow + (((size_t)b * 2048 + m0 + m) << 8) + G * 8);
      *(uint4*)&kr[m * 264 + G * 8] = v;
    }
    __syncthreads();

    f4v sacc[2];
    sacc[0] = f4v{0.f, 0.f, 0.f, 0.f};
    sacc[1] = f4v{0.f, 0.f, 0.f, 0.f};
#pragma unroll
    for (int s = 0; s < 8; ++s) {
#pragma unroll
      for (int f = 0; f < 2; ++f) {
        const s8v bf = *(const s8v*)&kr[(f * 16 + lr) * 264 + s * 32 + lh * 8];
        sacc[f] = __builtin_amdgcn_mfma_f32_16x16x32_bf16(qf[s], bf, sacc[f], 0, 0, 0);
      }
    }
#pragma unroll
    for (int f = 0; f < 2; ++f) {
      const int m = m0 + f * 16 + lr;
      const bool vm = m < mlen;
#pragma unroll
      for (int r = 0; r < 4; ++r) {
        float p = exp2f(sacc[f][r] * C2);
        if (!vm) p = 0.f;
        if (qrow0 + r >= qlen) p = 1.f;
        psum[r] += p;
      }
    }
    __syncthreads();
  }

#pragma unroll
  for (int r = 0; r < 4; ++r) {
    float v = psum[r];
    v += __shfl_xor(v, 1);
    v += __shfl_xor(v, 2);
    v += __shfl_xor(v, 4);
    v += __shfl_xor(v, 8);
    psum[r] = v;
  }
  if (lr == 0) {
#pragma unroll
    for (int r = 0; r < 4; ++r)
      psum_p[ms * 16384 + b * 2048 + qrow0 + r] = psum[r];
  }
}

// ---------------------------------------------------------------------------
// Kernel 3: write pass (round-5 form, z=2 -> z=4 for occupancy; LDS 39.5 KB
// via kc pad 36; plain full-line stores). P normalized up front; writes
// alignments once and accumulates ctx partials: mh=0 -> out_ctx, 1-3 -> ws.
// ---------------------------------------------------------------------------
__global__ __launch_bounds__(256) void attn_wr_kernel(
    const u16* __restrict__ qb, const u16* __restrict__ krow,
    const u16* __restrict__ kcol, const int* __restrict__ mlens,
    const int* __restrict__ qlens, const float* __restrict__ psum_p,
    float* __restrict__ out_align, float* __restrict__ out_ctx,
    float* __restrict__ octx_ws)
{
  __shared__ u16 kr[32 * 264];   // 16896 B
  __shared__ u16 kc[256 * 36];   // 18432 B  (pad 36: bank-starts 18*lr%32 distinct)
  __shared__ u16 pl[4 * 16 * 40]; // 5120 B   -> total 40448 B

  const int tid = threadIdx.x;
  const int w = tid >> 6;
  const int l = tid & 63;
  const int lr = l & 15;
  const int lh = l >> 4;
  const int b = blockIdx.y;
  const int q0 = blockIdx.x * 64;
  const int mh = blockIdx.z;
  const int m_base = mh * 512;
  const int mlen = mlens[b];
  const int qlen = qlens[b];
  const int qrow0 = q0 + w * 16 + lh * 4;

  s8v qf[8];
  {
    const u16* qp = qb + ((size_t)b * 2048 + q0 + w * 16 + lr) * 256 + lh * 8;
#pragma unroll
    for (int s = 0; s < 8; ++s) qf[s] = *(const s8v*)(qp + s * 32);
  }

  float inv[4];
#pragma unroll
  for (int r = 0; r < 4; ++r) {
    const int q = b * 2048 + qrow0 + r;
    float s = psum_p[q] + psum_p[16384 + q] + psum_p[32768 + q] + psum_p[49152 + q];
    inv[r] = 1.0f / s;
  }

  f4v oacc[16];
#pragma unroll
  for (int i = 0; i < 16; ++i) oacc[i] = f4v{0.f, 0.f, 0.f, 0.f};

  const float C2 = 0.09016844005556021f;  // log2(e)/16

  for (int mo = 0; mo < 512; mo += 32) {
    const int m0 = m_base + mo;
#pragma unroll
    for (int i = 0; i < 4; ++i) {
      const int idx = i * 256 + tid;
      const int m = idx >> 5, G = idx & 31;
      uint4 v = *(const uint4*)(krow + (((size_t)b * 2048 + m0 + m) << 8) + G * 8);
      *(uint4*)&kr[m * 264 + G * 8] = v;
      const int a2 = idx >> 2, gm = idx & 3;
      uint4 v2 = *(const uint4*)(kcol + (((size_t)b * 256 + a2) << 11) + m0 + gm * 8);
      *(uint4*)&kc[a2 * 36 + gm * 8] = v2;
    }
    __syncthreads();

    f4v sacc[2];
    sacc[0] = f4v{0.f, 0.f, 0.f, 0.f};
    sacc[1] = f4v{0.f, 0.f, 0.f, 0.f};
#pragma unroll
    for (int s = 0; s < 8; ++s) {
#pragma unroll
      for (int f = 0; f < 2; ++f) {
        const s8v bf = *(const s8v*)&kr[(f * 16 + lr) * 264 + s * 32 + lh * 8];
        sacc[f] = __builtin_amdgcn_mfma_f32_16x16x32_bf16(qf[s], bf, sacc[f], 0, 0, 0);
      }
    }

#pragma unroll
    for (int f = 0; f < 2; ++f) {
      const int m = m0 + f * 16 + lr;
      const bool vm = m < mlen;
#pragma unroll
      for (int r = 0; r < 4; ++r) {
        const int q = qrow0 + r;
        float p = exp2f(sacc[f][r] * C2);
        if (!vm) p = 0.f;
        if (q >= qlen) p = 1.f;
        const float pn = p * inv[r];
        // full-line-per-instruction store: 16 lanes (lr) x 4B contiguous
        out_align[((size_t)b * 2048 + q) * 2048 + m] = pn;
        pl[w * 640 + (lh * 4 + r) * 40 + f * 16 + lr] = f2bf(pn);
      }
    }

    const s8v pa = *(const s8v*)&pl[w * 640 + lr * 40 + lh * 8];
#pragma unroll
    for (int at = 0; at < 16; ++at) {
      const s8v vf = *(const s8v*)&kc[(at * 16 + lr) * 36 + lh * 8];
      oacc[at] = __builtin_amdgcn_mfma_f32_16x16x32_bf16(pa, vf, oacc[at], 0, 0, 0);
    }
    __syncthreads();
  }

  float* __restrict__ dst = (mh == 0) ? out_ctx : (octx_ws + (size_t)(mh - 1) * 4194304);
#pragma unroll
  for (int at = 0; at < 16; ++at) {
    const int a = at * 16 + lr;
#pragma unroll
    for (int r = 0; r < 4; ++r) {
      dst[((size_t)b * 2048 + qrow0 + r) * 256 + a] = oacc[at][r];
    }
  }
}

// ---------------------------------------------------------------------------
// Kernel 4: out_ctx += octx_ws[0..2] (combine the four M-quarter partials)
// ---------------------------------------------------------------------------
__global__ __launch_bounds__(256) void combine_kernel(
    float* __restrict__ out_ctx, const float* __restrict__ octx_ws)
{
  const size_t i = (size_t)blockIdx.x * 256 + threadIdx.x;
  float4 a = ((const float4*)out_ctx)[i];
  float4 c0 = ((const float4*)octx_ws)[i];
  float4 c1 = ((const float4*)(octx_ws + 4194304))[i];
  float4 c2 = ((const float4*)(octx_ws + 8388608))[i];
  a.x += c0.x + c1.x + c2.x;
  a.y += c0.y + c1.y + c2.y;
  a.z += c0.z + c1.z + c2.z;
  a.w += c0.w + c1.w + c2.w;
  ((float4*)out_ctx)[i] = a;
}

extern "C" void kernel_launch(void* const* d_in, const int* in_sizes, int n_in,
                              void* d_out, int out_size, void* d_ws, size_t ws_size,
                              hipStream_t stream) {
  const float* inputs = (const float*)d_in[0];   // [8,2048,512]
  const float* memory = (const float*)d_in[1];   // [8,2048,512]
  const int* mlens    = (const int*)d_in[2];     // [8]
  const int* qlens    = (const int*)d_in[3];     // [8]
  const float* Wq     = (const float*)d_in[4];   // [512,256]
  const float* Wk     = (const float*)d_in[5];   // [512,256]
  (void)in_sizes; (void)n_in; (void)out_size; (void)ws_size;

  u16* wsu = (u16*)d_ws;
  u16* qb   = wsu;                        // 4194304 u16 (8 MB)
  u16* krow = wsu + 4194304;              // 4194304 u16 (8 MB)
  u16* kcol = wsu + 8388608;              // 4194304 u16 (8 MB)
  float* psum_p = (float*)(wsu + 12582912);   // 4*16384 f32 (256 KB)
  float* octx_ws = (float*)(wsu + 12713984);  // 3*4194304 f32 (50.3 MB)

  float* out_ctx = (float*)d_out;             // [8,2048,256]
  float* out_align = out_ctx + 4194304;       // [8,2048,2048]

  proj_kernel<<<dim3(256, 4, 2), dim3(256), 0, stream>>>(
      inputs, memory, Wq, Wk, qb, krow, kcol);
  attn_sum_kernel<<<dim3(32, 8, 4), dim3(256), 0, stream>>>(
      qb, krow, mlens, qlens, psum_p);
  attn_wr_kernel<<<dim3(32, 8, 4), dim3(256), 0, stream>>>(
      qb, krow, kcol, mlens, qlens, psum_p, out_align, out_ctx, octx_ws);
  combine_kernel<<<dim3(4096), dim3(256), 0, stream>>>(out_ctx, octx_ws);
}

// Round 12
// 223.226 us; speedup vs baseline: 1.5466x; 1.0933x over previous
//
#include <hip/hip_runtime.h>
#include <hip/hip_bf16.h>

typedef __attribute__((ext_vector_type(8))) short s8v;   // 8 x bf16 MFMA operand
typedef __attribute__((ext_vector_type(4))) float f4v;   // MFMA accumulator
typedef __attribute__((ext_vector_type(4))) unsigned short us4;
typedef unsigned short u16;

__device__ __forceinline__ u16 f2bf(float f) {
  union { float f; unsigned int u; } x;
  x.f = f;
  unsigned int lsb = (x.u >> 16) & 1u;
  return (u16)((x.u + 0x7fffu + lsb) >> 16);
}

__device__ __forceinline__ uint4 pack8(float4 a, float4 b) {
  union { u16 u[8]; uint4 v; } t;
  t.u[0] = f2bf(a.x); t.u[1] = f2bf(a.y); t.u[2] = f2bf(a.z); t.u[3] = f2bf(a.w);
  t.u[4] = f2bf(b.x); t.u[5] = f2bf(b.y); t.u[6] = f2bf(b.z); t.u[7] = f2bf(b.w);
  return t.v;
}

// ---------------------------------------------------------------------------
// Kernel 1: projections (r5-identical). C[16384x256] = A[16384x512]@W[512x256]
// src=0: queries -> qb row-major; src=1: keys -> krow row-major + kcol [b][a][m]
// ---------------------------------------------------------------------------
__global__ __launch_bounds__(256) void proj_kernel(
    const float* __restrict__ inputs, const float* __restrict__ memory,
    const float* __restrict__ Wq, const float* __restrict__ Wk,
    u16* __restrict__ qb, u16* __restrict__ krow, u16* __restrict__ kcol)
{
  __shared__ u16 Wt[64 * 264];
  __shared__ u16 At[64 * 40];

  const int tid = threadIdx.x;
  const int w = tid >> 6;
  const int l = tid & 63;
  const int lr = l & 15;
  const int lh = l >> 4;
  const int rbase = blockIdx.x * 64;
  const int n0 = blockIdx.y * 64;
  const int src = blockIdx.z;
  const float* __restrict__ A  = src ? memory : inputs;
  const float* __restrict__ Wg = src ? Wk : Wq;

  f4v acc[4];
#pragma unroll
  for (int i = 0; i < 4; ++i) acc[i] = f4v{0.f, 0.f, 0.f, 0.f};

  for (int kh = 0; kh < 2; ++kh) {
    {
      const int kl = tid >> 3;
      const int nl = (tid & 7) * 8;
#pragma unroll
      for (int i = 0; i < 8; ++i) {
        const int k = kl + i * 32;
        const float* s = Wg + (size_t)(kh * 256 + k) * 256 + n0 + nl;
        float4 x0 = *(const float4*)s;
        float4 x1 = *(const float4*)(s + 4);
        Wt[(nl + 0) * 264 + k] = f2bf(x0.x);
        Wt[(nl + 1) * 264 + k] = f2bf(x0.y);
        Wt[(nl + 2) * 264 + k] = f2bf(x0.z);
        Wt[(nl + 3) * 264 + k] = f2bf(x0.w);
        Wt[(nl + 4) * 264 + k] = f2bf(x1.x);
        Wt[(nl + 5) * 264 + k] = f2bf(x1.y);
        Wt[(nl + 6) * 264 + k] = f2bf(x1.z);
        Wt[(nl + 7) * 264 + k] = f2bf(x1.w);
      }
    }
    __syncthreads();
    for (int ks = 0; ks < 8; ++ks) {
      {
        const int row = tid >> 2;
        const int kk = (tid & 3) * 8;
        const float* s = A + (size_t)(rbase + row) * 512 + kh * 256 + ks * 32 + kk;
        float4 x0 = *(const float4*)s;
        float4 x1 = *(const float4*)(s + 4);
        *(uint4*)&At[row * 40 + kk] = pack8(x0, x1);
      }
      __syncthreads();
      const s8v af = *(const s8v*)&At[(w * 16 + lr) * 40 + lh * 8];
#pragma unroll
      for (int nt = 0; nt < 4; ++nt) {
        const s8v bf = *(const s8v*)&Wt[(nt * 16 + lr) * 264 + ks * 32 + lh * 8];
        acc[nt] = __builtin_amdgcn_mfma_f32_16x16x32_bf16(af, bf, acc[nt], 0, 0, 0);
      }
      __syncthreads();
    }
  }

  u16* __restrict__ dst = src ? krow : qb;
#pragma unroll
  for (int nt = 0; nt < 4; ++nt) {
    const int col = n0 + nt * 16 + lr;
    const int R0 = rbase + w * 16 + lh * 4;
    u16 u0 = f2bf(acc[nt][0]);
    u16 u1 = f2bf(acc[nt][1]);
    u16 u2 = f2bf(acc[nt][2]);
    u16 u3 = f2bf(acc[nt][3]);
    dst[(size_t)(R0 + 0) * 256 + col] = u0;
    dst[(size_t)(R0 + 1) * 256 + col] = u1;
    dst[(size_t)(R0 + 2) * 256 + col] = u2;
    dst[(size_t)(R0 + 3) * 256 + col] = u3;
    if (src) {
      const int bb = R0 >> 11;
      const int mm = R0 & 2047;
      us4 pk;
      pk[0] = u0; pk[1] = u1; pk[2] = u2; pk[3] = u3;
      *(us4*)&kcol[((size_t)bb * 256 + col) * 2048 + mm] = pk;
    }
  }
}

// ---------------------------------------------------------------------------
// Kernel 2: row-sum pass. 64-m tiles (was 32): 2x compute per barrier to
// cover staging latency, half the barriers, 4 independent QK MFMA chains.
// 64 q x 512 m per block, 4-way M split.
// ---------------------------------------------------------------------------
__global__ __launch_bounds__(256) void attn_sum_kernel(
    const u16* __restrict__ qb, const u16* __restrict__ krow,
    const int* __restrict__ mlens, const int* __restrict__ qlens,
    float* __restrict__ psum_p)
{
  __shared__ u16 kr[64 * 264];   // 33792 B -> 4 blocks/CU

  const int tid = threadIdx.x;
  const int w = tid >> 6;
  const int l = tid & 63;
  const int lr = l & 15;
  const int lh = l >> 4;
  const int b = blockIdx.y;
  const int q0 = blockIdx.x * 64;
  const int ms = blockIdx.z;
  const int m_base = ms * 512;
  const int mlen = mlens[b];
  const int qlen = qlens[b];
  const int qrow0 = q0 + w * 16 + lh * 4;

  s8v qf[8];
  {
    const u16* qp = qb + ((size_t)b * 2048 + q0 + w * 16 + lr) * 256 + lh * 8;
#pragma unroll
    for (int s = 0; s < 8; ++s) qf[s] = *(const s8v*)(qp + s * 32);
  }

  float psum[4] = {0.f, 0.f, 0.f, 0.f};
  const float C2 = 0.09016844005556021f;  // log2(e)/16

  for (int mo = 0; mo < 512; mo += 64) {
    const int m0 = m_base + mo;
#pragma unroll
    for (int i = 0; i < 8; ++i) {
      const int idx = i * 256 + tid;
      const int m = idx >> 5, G = idx & 31;
      uint4 v = *(const uint4*)(krow + (((size_t)b * 2048 + m0 + m) << 8) + G * 8);
      *(uint4*)&kr[m * 264 + G * 8] = v;
    }
    __syncthreads();

    f4v sacc[4];
#pragma unroll
    for (int f = 0; f < 4; ++f) sacc[f] = f4v{0.f, 0.f, 0.f, 0.f};
#pragma unroll
    for (int s = 0; s < 8; ++s) {
#pragma unroll
      for (int f = 0; f < 4; ++f) {
        const s8v bf = *(const s8v*)&kr[(f * 16 + lr) * 264 + s * 32 + lh * 8];
        sacc[f] = __builtin_amdgcn_mfma_f32_16x16x32_bf16(qf[s], bf, sacc[f], 0, 0, 0);
      }
    }
#pragma unroll
    for (int f = 0; f < 4; ++f) {
      const int m = m0 + f * 16 + lr;
      const bool vm = m < mlen;
#pragma unroll
      for (int r = 0; r < 4; ++r) {
        float p = exp2f(sacc[f][r] * C2);
        if (!vm) p = 0.f;
        if (qrow0 + r >= qlen) p = 1.f;
        psum[r] += p;
      }
    }
    __syncthreads();
  }

#pragma unroll
  for (int r = 0; r < 4; ++r) {
    float v = psum[r];
    v += __shfl_xor(v, 1);
    v += __shfl_xor(v, 2);
    v += __shfl_xor(v, 4);
    v += __shfl_xor(v, 8);
    psum[r] = v;
  }
  if (lr == 0) {
#pragma unroll
    for (int r = 0; r < 4; ++r)
      psum_p[ms * 16384 + b * 2048 + qrow0 + r] = psum[r];
  }
}

// ---------------------------------------------------------------------------
// Kernel 3: write pass (r5 dataflow, z=2). 64-m tiles: kr 33.8KB + kc 34.8KB
// + pl 9.2KB = 77.8KB -> 2 blocks/CU (same as r5) but half the barriers and
// double per-barrier compute. P normalized up front; alignments written once
// (full-line pattern); ctx partial mh=0 -> out_ctx, mh=1 -> ws.
// ---------------------------------------------------------------------------
__global__ __launch_bounds__(256) void attn_wr_kernel(
    const u16* __restrict__ qb, const u16* __restrict__ krow,
    const u16* __restrict__ kcol, const int* __restrict__ mlens,
    const int* __restrict__ qlens, const float* __restrict__ psum_p,
    float* __restrict__ out_align, float* __restrict__ out_ctx,
    float* __restrict__ octx1)
{
  __shared__ u16 kr[64 * 264];    // [m][a] padded
  __shared__ u16 kc[256 * 68];    // [a][m 64] pad 68 (4-way worst on vf reads)
  __shared__ u16 pl[4 * 16 * 72]; // per-wave [16 q][64 m] pad 72

  const int tid = threadIdx.x;
  const int w = tid >> 6;
  const int l = tid & 63;
  const int lr = l & 15;
  const int lh = l >> 4;
  const int b = blockIdx.y;
  const int q0 = blockIdx.x * 64;
  const int mh = blockIdx.z;
  const int m_base = mh * 1024;
  const int mlen = mlens[b];
  const int qlen = qlens[b];
  const int qrow0 = q0 + w * 16 + lh * 4;

  s8v qf[8];
  {
    const u16* qp = qb + ((size_t)b * 2048 + q0 + w * 16 + lr) * 256 + lh * 8;
#pragma unroll
    for (int s = 0; s < 8; ++s) qf[s] = *(const s8v*)(qp + s * 32);
  }

  float inv[4];
#pragma unroll
  for (int r = 0; r < 4; ++r) {
    const int q = b * 2048 + qrow0 + r;
    float s = psum_p[q] + psum_p[16384 + q] + psum_p[32768 + q] + psum_p[49152 + q];
    inv[r] = 1.0f / s;
  }

  f4v oacc[16];
#pragma unroll
  for (int i = 0; i < 16; ++i) oacc[i] = f4v{0.f, 0.f, 0.f, 0.f};

  const float C2 = 0.09016844005556021f;  // log2(e)/16

  for (int mo = 0; mo < 1024; mo += 64) {
    const int m0 = m_base + mo;
    // stage K tile [64 m][256 a] and V tile [256 a][64 m]
#pragma unroll
    for (int i = 0; i < 8; ++i) {
      const int idx = i * 256 + tid;
      const int m = idx >> 5, G = idx & 31;
      uint4 v = *(const uint4*)(krow + (((size_t)b * 2048 + m0 + m) << 8) + G * 8);
      *(uint4*)&kr[m * 264 + G * 8] = v;
      const int a2 = idx >> 3, gm = idx & 7;
      uint4 v2 = *(const uint4*)(kcol + (((size_t)b * 256 + a2) << 11) + m0 + gm * 8);
      *(uint4*)&kc[a2 * 68 + gm * 8] = v2;
    }
    __syncthreads();

    f4v sacc[4];
#pragma unroll
    for (int f = 0; f < 4; ++f) sacc[f] = f4v{0.f, 0.f, 0.f, 0.f};
#pragma unroll
    for (int s = 0; s < 8; ++s) {
#pragma unroll
      for (int f = 0; f < 4; ++f) {
        const s8v bf = *(const s8v*)&kr[(f * 16 + lr) * 264 + s * 32 + lh * 8];
        sacc[f] = __builtin_amdgcn_mfma_f32_16x16x32_bf16(qf[s], bf, sacc[f], 0, 0, 0);
      }
    }

#pragma unroll
    for (int f = 0; f < 4; ++f) {
      const int m = m0 + f * 16 + lr;
      const bool vm = m < mlen;
#pragma unroll
      for (int r = 0; r < 4; ++r) {
        const int q = qrow0 + r;
        float p = exp2f(sacc[f][r] * C2);
        if (!vm) p = 0.f;
        if (q >= qlen) p = 1.f;
        const float pn = p * inv[r];
        out_align[((size_t)b * 2048 + q) * 2048 + m] = pn;   // full-line store
        pl[w * 1152 + (lh * 4 + r) * 72 + f * 16 + lr] = f2bf(pn);
      }
    }

    // PV: two K=32 slices over the 64-m tile
#pragma unroll
    for (int ks = 0; ks < 2; ++ks) {
      const s8v pa = *(const s8v*)&pl[w * 1152 + lr * 72 + ks * 32 + lh * 8];
#pragma unroll
      for (int at = 0; at < 16; ++at) {
        const s8v vf = *(const s8v*)&kc[(at * 16 + lr) * 68 + ks * 32 + lh * 8];
        oacc[at] = __builtin_amdgcn_mfma_f32_16x16x32_bf16(pa, vf, oacc[at], 0, 0, 0);
      }
    }
    __syncthreads();
  }

  float* __restrict__ dst = mh ? octx1 : out_ctx;
#pragma unroll
  for (int at = 0; at < 16; ++at) {
    const int a = at * 16 + lr;
#pragma unroll
    for (int r = 0; r < 4; ++r) {
      dst[((size_t)b * 2048 + qrow0 + r) * 256 + a] = oacc[at][r];
    }
  }
}

// ---------------------------------------------------------------------------
// Kernel 4: out_ctx += octx1
// ---------------------------------------------------------------------------
__global__ __launch_bounds__(256) void combine_kernel(
    float* __restrict__ out_ctx, const float* __restrict__ octx1)
{
  const size_t i = (size_t)blockIdx.x * 256 + threadIdx.x;
  float4 a = ((const float4*)out_ctx)[i];
  float4 c = ((const float4*)octx1)[i];
  a.x += c.x; a.y += c.y; a.z += c.z; a.w += c.w;
  ((float4*)out_ctx)[i] = a;
}

extern "C" void kernel_launch(void* const* d_in, const int* in_sizes, int n_in,
                              void* d_out, int out_size, void* d_ws, size_t ws_size,
                              hipStream_t stream) {
  const float* inputs = (const float*)d_in[0];   // [8,2048,512]
  const float* memory = (const float*)d_in[1];   // [8,2048,512]
  const int* mlens    = (const int*)d_in[2];     // [8]
  const int* qlens    = (const int*)d_in[3];     // [8]
  const float* Wq     = (const float*)d_in[4];   // [512,256]
  const float* Wk     = (const float*)d_in[5];   // [512,256]
  (void)in_sizes; (void)n_in; (void)out_size; (void)ws_size;

  u16* wsu = (u16*)d_ws;
  u16* qb   = wsu;                        // 4194304 u16 (8 MB)
  u16* krow = wsu + 4194304;              // 4194304 u16 (8 MB)
  u16* kcol = wsu + 8388608;              // 4194304 u16 (8 MB)
  float* psum_p = (float*)(wsu + 12582912);   // 4*16384 f32 (256 KB)
  float* octx1  = psum_p + 65536;             // 4194304 f32 (16.8 MB)

  float* out_ctx = (float*)d_out;             // [8,2048,256]
  float* out_align = out_ctx + 4194304;       // [8,2048,2048]

  proj_kernel<<<dim3(256, 4, 2), dim3(256), 0, stream>>>(
      inputs, memory, Wq, Wk, qb, krow, kcol);
  attn_sum_kernel<<<dim3(32, 8, 4), dim3(256), 0, stream>>>(
      qb, krow, mlens, qlens, psum_p);
  attn_wr_kernel<<<dim3(32, 8, 2), dim3(256), 0, stream>>>(
      qb, krow, kcol, mlens, qlens, psum_p, out_align, out_ctx, octx1);
  combine_kernel<<<dim3(4096), dim3(256), 0, stream>>>(out_ctx, octx1);
}

// Round 13
// 176.103 us; speedup vs baseline: 1.9605x; 1.2676x over previous
//
#include <hip/hip_runtime.h>
#include <hip/hip_bf16.h>

typedef __attribute__((ext_vector_type(8))) short s8v;   // 8 x bf16 MFMA operand
typedef __attribute__((ext_vector_type(4))) float f4v;   // MFMA accumulator
typedef __attribute__((ext_vector_type(4))) unsigned short us4;
typedef unsigned short u16;

__device__ __forceinline__ u16 f2bf(float f) {
  union { float f; unsigned int u; } x;
  x.f = f;
  unsigned int lsb = (x.u >> 16) & 1u;
  return (u16)((x.u + 0x7fffu + lsb) >> 16);
}

__device__ __forceinline__ uint4 pack8(float4 a, float4 b) {
  union { u16 u[8]; uint4 v; } t;
  t.u[0] = f2bf(a.x); t.u[1] = f2bf(a.y); t.u[2] = f2bf(a.z); t.u[3] = f2bf(a.w);
  t.u[4] = f2bf(b.x); t.u[5] = f2bf(b.y); t.u[6] = f2bf(b.z); t.u[7] = f2bf(b.w);
  return t.v;
}

// ---------------------------------------------------------------------------
// Kernel 1: projections (r5-identical). C[16384x256] = A[16384x512]@W[512x256]
// ---------------------------------------------------------------------------
__global__ __launch_bounds__(256) void proj_kernel(
    const float* __restrict__ inputs, const float* __restrict__ memory,
    const float* __restrict__ Wq, const float* __restrict__ Wk,
    u16* __restrict__ qb, u16* __restrict__ krow, u16* __restrict__ kcol)
{
  __shared__ u16 Wt[64 * 264];
  __shared__ u16 At[64 * 40];

  const int tid = threadIdx.x;
  const int w = tid >> 6;
  const int l = tid & 63;
  const int lr = l & 15;
  const int lh = l >> 4;
  const int rbase = blockIdx.x * 64;
  const int n0 = blockIdx.y * 64;
  const int src = blockIdx.z;
  const float* __restrict__ A  = src ? memory : inputs;
  const float* __restrict__ Wg = src ? Wk : Wq;

  f4v acc[4];
#pragma unroll
  for (int i = 0; i < 4; ++i) acc[i] = f4v{0.f, 0.f, 0.f, 0.f};

  for (int kh = 0; kh < 2; ++kh) {
    {
      const int kl = tid >> 3;
      const int nl = (tid & 7) * 8;
#pragma unroll
      for (int i = 0; i < 8; ++i) {
        const int k = kl + i * 32;
        const float* s = Wg + (size_t)(kh * 256 + k) * 256 + n0 + nl;
        float4 x0 = *(const float4*)s;
        float4 x1 = *(const float4*)(s + 4);
        Wt[(nl + 0) * 264 + k] = f2bf(x0.x);
        Wt[(nl + 1) * 264 + k] = f2bf(x0.y);
        Wt[(nl + 2) * 264 + k] = f2bf(x0.z);
        Wt[(nl + 3) * 264 + k] = f2bf(x0.w);
        Wt[(nl + 4) * 264 + k] = f2bf(x1.x);
        Wt[(nl + 5) * 264 + k] = f2bf(x1.y);
        Wt[(nl + 6) * 264 + k] = f2bf(x1.z);
        Wt[(nl + 7) * 264 + k] = f2bf(x1.w);
      }
    }
    __syncthreads();
    for (int ks = 0; ks < 8; ++ks) {
      {
        const int row = tid >> 2;
        const int kk = (tid & 3) * 8;
        const float* s = A + (size_t)(rbase + row) * 512 + kh * 256 + ks * 32 + kk;
        float4 x0 = *(const float4*)s;
        float4 x1 = *(const float4*)(s + 4);
        *(uint4*)&At[row * 40 + kk] = pack8(x0, x1);
      }
      __syncthreads();
      const s8v af = *(const s8v*)&At[(w * 16 + lr) * 40 + lh * 8];
#pragma unroll
      for (int nt = 0; nt < 4; ++nt) {
        const s8v bf = *(const s8v*)&Wt[(nt * 16 + lr) * 264 + ks * 32 + lh * 8];
        acc[nt] = __builtin_amdgcn_mfma_f32_16x16x32_bf16(af, bf, acc[nt], 0, 0, 0);
      }
      __syncthreads();
    }
  }

  u16* __restrict__ dst = src ? krow : qb;
#pragma unroll
  for (int nt = 0; nt < 4; ++nt) {
    const int col = n0 + nt * 16 + lr;
    const int R0 = rbase + w * 16 + lh * 4;
    u16 u0 = f2bf(acc[nt][0]);
    u16 u1 = f2bf(acc[nt][1]);
    u16 u2 = f2bf(acc[nt][2]);
    u16 u3 = f2bf(acc[nt][3]);
    dst[(size_t)(R0 + 0) * 256 + col] = u0;
    dst[(size_t)(R0 + 1) * 256 + col] = u1;
    dst[(size_t)(R0 + 2) * 256 + col] = u2;
    dst[(size_t)(R0 + 3) * 256 + col] = u3;
    if (src) {
      const int bb = R0 >> 11;
      const int mm = R0 & 2047;
      us4 pk;
      pk[0] = u0; pk[1] = u1; pk[2] = u2; pk[3] = u3;
      *(us4*)&kcol[((size_t)bb * 256 + col) * 2048 + mm] = pk;
    }
  }
}

// ---------------------------------------------------------------------------
// Kernel 2: row-sum pass (r5-identical except 1D grid with b = blockid&7 so
// all blocks of batch b land on XCD b -> qb/krow slices L2-resident).
// ---------------------------------------------------------------------------
__global__ __launch_bounds__(256) void attn_sum_kernel(
    const u16* __restrict__ qb, const u16* __restrict__ krow,
    const int* __restrict__ mlens, const int* __restrict__ qlens,
    float* __restrict__ psum_p)
{
  __shared__ u16 kr[32 * 264];

  const int tid = threadIdx.x;
  const int w = tid >> 6;
  const int l = tid & 63;
  const int lr = l & 15;
  const int lh = l >> 4;
  const int bid = blockIdx.x;
  const int b = bid & 7;                    // XCD-pin: id%8 == b
  const int q0 = ((bid >> 3) & 31) * 64;
  const int ms = bid >> 8;
  const int m_base = ms * 512;
  const int mlen = mlens[b];
  const int qlen = qlens[b];
  const int qrow0 = q0 + w * 16 + lh * 4;

  s8v qf[8];
  {
    const u16* qp = qb + ((size_t)b * 2048 + q0 + w * 16 + lr) * 256 + lh * 8;
#pragma unroll
    for (int s = 0; s < 8; ++s) qf[s] = *(const s8v*)(qp + s * 32);
  }

  float psum[4] = {0.f, 0.f, 0.f, 0.f};
  const float C2 = 0.09016844005556021f;  // log2(e)/16

  for (int mo = 0; mo < 512; mo += 32) {
    const int m0 = m_base + mo;
#pragma unroll
    for (int i = 0; i < 4; ++i) {
      const int idx = i * 256 + tid;
      const int m = idx >> 5, G = idx & 31;
      uint4 v = *(const uint4*)(krow + (((size_t)b * 2048 + m0 + m) << 8) + G * 8);
      *(uint4*)&kr[m * 264 + G * 8] = v;
    }
    __syncthreads();

    f4v sacc[2];
    sacc[0] = f4v{0.f, 0.f, 0.f, 0.f};
    sacc[1] = f4v{0.f, 0.f, 0.f, 0.f};
#pragma unroll
    for (int s = 0; s < 8; ++s) {
#pragma unroll
      for (int f = 0; f < 2; ++f) {
        const s8v bf = *(const s8v*)&kr[(f * 16 + lr) * 264 + s * 32 + lh * 8];
        sacc[f] = __builtin_amdgcn_mfma_f32_16x16x32_bf16(qf[s], bf, sacc[f], 0, 0, 0);
      }
    }
#pragma unroll
    for (int f = 0; f < 2; ++f) {
      const int m = m0 + f * 16 + lr;
      const bool vm = m < mlen;
#pragma unroll
      for (int r = 0; r < 4; ++r) {
        float p = exp2f(sacc[f][r] * C2);
        if (!vm) p = 0.f;
        if (qrow0 + r >= qlen) p = 1.f;
        psum[r] += p;
      }
    }
    __syncthreads();
  }

#pragma unroll
  for (int r = 0; r < 4; ++r) {
    float v = psum[r];
    v += __shfl_xor(v, 1);
    v += __shfl_xor(v, 2);
    v += __shfl_xor(v, 4);
    v += __shfl_xor(v, 8);
    psum[r] = v;
  }
  if (lr == 0) {
#pragma unroll
    for (int r = 0; r < 4; ++r)
      psum_p[ms * 16384 + b * 2048 + qrow0 + r] = psum[r];
  }
}

// ---------------------------------------------------------------------------
// Kernel 3: write pass (r5-identical geometry: 32-m tiles, z=2 -> 42.5 KB LDS
// -> 3 blocks/CU; 1D grid with b = blockid&7 for XCD pinning).
// ---------------------------------------------------------------------------
__global__ __launch_bounds__(256) void attn_wr_kernel(
    const u16* __restrict__ qb, const u16* __restrict__ krow,
    const u16* __restrict__ kcol, const int* __restrict__ mlens,
    const int* __restrict__ qlens, const float* __restrict__ psum_p,
    float* __restrict__ out_align, float* __restrict__ out_ctx,
    float* __restrict__ octx1)
{
  __shared__ u16 kr[32 * 264];
  __shared__ u16 kc[256 * 40];
  __shared__ u16 pl[4 * 16 * 40];

  const int tid = threadIdx.x;
  const int w = tid >> 6;
  const int l = tid & 63;
  const int lr = l & 15;
  const int lh = l >> 4;
  const int bid = blockIdx.x;
  const int b = bid & 7;                    // XCD-pin: id%8 == b
  const int q0 = ((bid >> 3) & 31) * 64;
  const int mh = bid >> 8;
  const int m_base = mh * 1024;
  const int mlen = mlens[b];
  const int qlen = qlens[b];
  const int qrow0 = q0 + w * 16 + lh * 4;

  s8v qf[8];
  {
    const u16* qp = qb + ((size_t)b * 2048 + q0 + w * 16 + lr) * 256 + lh * 8;
#pragma unroll
    for (int s = 0; s < 8; ++s) qf[s] = *(const s8v*)(qp + s * 32);
  }

  float inv[4];
#pragma unroll
  for (int r = 0; r < 4; ++r) {
    const int q = b * 2048 + qrow0 + r;
    float s = psum_p[q] + psum_p[16384 + q] + psum_p[32768 + q] + psum_p[49152 + q];
    inv[r] = 1.0f / s;
  }

  f4v oacc[16];
#pragma unroll
  for (int i = 0; i < 16; ++i) oacc[i] = f4v{0.f, 0.f, 0.f, 0.f};

  const float C2 = 0.09016844005556021f;  // log2(e)/16

  for (int mo = 0; mo < 1024; mo += 32) {
    const int m0 = m_base + mo;
#pragma unroll
    for (int i = 0; i < 4; ++i) {
      const int idx = i * 256 + tid;
      const int m = idx >> 5, G = idx & 31;
      uint4 v = *(const uint4*)(krow + (((size_t)b * 2048 + m0 + m) << 8) + G * 8);
      *(uint4*)&kr[m * 264 + G * 8] = v;
      const int a2 = idx >> 2, gm = idx & 3;
      uint4 v2 = *(const uint4*)(kcol + (((size_t)b * 256 + a2) << 11) + m0 + gm * 8);
      *(uint4*)&kc[a2 * 40 + gm * 8] = v2;
    }
    __syncthreads();

    f4v sacc[2];
    sacc[0] = f4v{0.f, 0.f, 0.f, 0.f};
    sacc[1] = f4v{0.f, 0.f, 0.f, 0.f};
#pragma unroll
    for (int s = 0; s < 8; ++s) {
#pragma unroll
      for (int f = 0; f < 2; ++f) {
        const s8v bf = *(const s8v*)&kr[(f * 16 + lr) * 264 + s * 32 + lh * 8];
        sacc[f] = __builtin_amdgcn_mfma_f32_16x16x32_bf16(qf[s], bf, sacc[f], 0, 0, 0);
      }
    }

#pragma unroll
    for (int f = 0; f < 2; ++f) {
      const int m = m0 + f * 16 + lr;
      const bool vm = m < mlen;
#pragma unroll
      for (int r = 0; r < 4; ++r) {
        const int q = qrow0 + r;
        float p = exp2f(sacc[f][r] * C2);
        if (!vm) p = 0.f;
        if (q >= qlen) p = 1.f;
        const float pn = p * inv[r];
        __builtin_nontemporal_store(pn, &out_align[((size_t)b * 2048 + q) * 2048 + m]);
        pl[w * 640 + (lh * 4 + r) * 40 + f * 16 + lr] = f2bf(pn);
      }
    }

    const s8v pa = *(const s8v*)&pl[w * 640 + lr * 40 + lh * 8];
#pragma unroll
    for (int at = 0; at < 16; ++at) {
      const s8v vf = *(const s8v*)&kc[(at * 16 + lr) * 40 + lh * 8];
      oacc[at] = __builtin_amdgcn_mfma_f32_16x16x32_bf16(pa, vf, oacc[at], 0, 0, 0);
    }
    __syncthreads();
  }

  float* __restrict__ dst = mh ? octx1 : out_ctx;
#pragma unroll
  for (int at = 0; at < 16; ++at) {
    const int a = at * 16 + lr;
#pragma unroll
    for (int r = 0; r < 4; ++r) {
      __builtin_nontemporal_store(oacc[at][r],
          &dst[((size_t)b * 2048 + qrow0 + r) * 256 + a]);
    }
  }
}

// ---------------------------------------------------------------------------
// Kernel 4: out_ctx += octx1
// ---------------------------------------------------------------------------
__global__ __launch_bounds__(256) void combine_kernel(
    float* __restrict__ out_ctx, const float* __restrict__ octx1)
{
  const size_t i = (size_t)blockIdx.x * 256 + threadIdx.x;
  float4 a = ((const float4*)out_ctx)[i];
  float4 c = ((const float4*)octx1)[i];
  a.x += c.x; a.y += c.y; a.z += c.z; a.w += c.w;
  ((float4*)out_ctx)[i] = a;
}

extern "C" void kernel_launch(void* const* d_in, const int* in_sizes, int n_in,
                              void* d_out, int out_size, void* d_ws, size_t ws_size,
                              hipStream_t stream) {
  const float* inputs = (const float*)d_in[0];   // [8,2048,512]
  const float* memory = (const float*)d_in[1];   // [8,2048,512]
  const int* mlens    = (const int*)d_in[2];     // [8]
  const int* qlens    = (const int*)d_in[3];     // [8]
  const float* Wq     = (const float*)d_in[4];   // [512,256]
  const float* Wk     = (const float*)d_in[5];   // [512,256]
  (void)in_sizes; (void)n_in; (void)out_size; (void)ws_size;

  u16* wsu = (u16*)d_ws;
  u16* qb   = wsu;                        // 4194304 u16 (8 MB)
  u16* krow = wsu + 4194304;              // 4194304 u16 (8 MB)
  u16* kcol = wsu + 8388608;              // 4194304 u16 (8 MB)
  float* psum_p = (float*)(wsu + 12582912);   // 4*16384 f32 (256 KB)
  float* octx1  = psum_p + 65536;             // 4194304 f32 (16.8 MB)

  float* out_ctx = (float*)d_out;             // [8,2048,256]
  float* out_align = out_ctx + 4194304;       // [8,2048,2048]

  proj_kernel<<<dim3(256, 4, 2), dim3(256), 0, stream>>>(
      inputs, memory, Wq, Wk, qb, krow, kcol);
  attn_sum_kernel<<<dim3(1024), dim3(256), 0, stream>>>(
      qb, krow, mlens, qlens, psum_p);
  attn_wr_kernel<<<dim3(512), dim3(256), 0, stream>>>(
      qb, krow, kcol, mlens, qlens, psum_p, out_align, out_ctx, octx1);
  combine_kernel<<<dim3(4096), dim3(256), 0, stream>>>(out_ctx, octx1);
}